// Round 3
// baseline (709.698 us; speedup 1.0000x reference)
//
#include <hip/hip_runtime.h>

// LeNet C3 masked conv, overwrite semantics: each output channel j is produced
// solely by the LAST input channel h with MASK[h][j]==1 (filter offset
// (h*10+pos)*25). Input channels 0,1 are dead.
//
// x:       [B, 6, 14, 14] f32   (only ch 2..5 read; contiguous float range
//                                [392, 1176) per batch)
// weights: [6, 10, 5, 5]  f32
// bias:    [16]           f32
// out:     [B, 16, 10, 10] f32
//
// R4 = R2 resubmitted, attempt 3. Both prior attempts died with "MI355X
// container failed twice" — a broker/acquisition-stage error emitted before
// compile or correctness ran. Source audited: all accesses in-bounds and
// aligned; launch path identical to the R1 kernel that passed. Not a kernel
// failure mode; do not mutate the experiment.
//
// R2 change vs R1: output LDS staging (51.2 KB) + copy-out barrier removed.
// Threads re-mapped 128 = 8 batches x 16 j; each thread computes its full
// 10x10 output plane with a 5-row register sliding window and stores pairs
// of rows directly to global as 5 aligned float4 (per-thread 400 B
// contiguous region -> L2 merges to full lines; write bytes unchanged).
// LDS drops 76.4 -> 24.8 KB: 2 -> 6 blocks/CU (8 -> 12 waves/CU), stores
// stream during compute instead of a barrier-serialized copy-out phase.

#define NB 8        // batches per block
#define THREADS 128 // 8 batches x 16 output channels
#define XPITCH 792  // per-batch LDS pitch in floats: 784 + 8 pad.
                    // 792 % 32 == 24 -> the 16 distinct (bloc,hrel) window
                    // read addrs per wave land exactly 2-way per bank pair
                    // (2-way is free); 792*4 % 16 == 0 keeps float4 staging.

__device__ __constant__ int C3_HREL[16] = {0,1,2,3,3,3,1,2,3,3,3,3,2,3,3,3}; // h-2
__device__ __constant__ int C3_WIDX[16] = {20,30,40,50,51,52,33,43,53,54,55,56,47,57,58,59};

__global__ __launch_bounds__(THREADS, 3)
void c3_kernel(const float* __restrict__ x,
               const float* __restrict__ w,
               const float* __restrict__ bias,
               float* __restrict__ out) {
    __shared__ float sx[NB * XPITCH];  // staged input planes (ch2..5), 24.75 KB

    const int t = threadIdx.x;

    // ---- Stage x: 8 batches x 196 float4 (contiguous 784-float segment per
    // batch starting at float 392 of the 1176-float batch record). ----
    {
        const float4* __restrict__ x4 = (const float4*)x;
        const long long base = (long long)blockIdx.x * NB;
#pragma unroll
        for (int i = 0; i < (NB * 196 + THREADS - 1) / THREADS; ++i) {
            int idx = t + i * THREADS;
            if (idx < NB * 196) {
                int bat = idx / 196;       // magic-mul
                int q   = idx - bat * 196;
                float4 v = x4[(base + bat) * 294 + 98 + q];
                *(float4*)&sx[bat * XPITCH + q * 4] = v;
            }
        }
    }

    const int j    = t & 15;  // output channel
    const int bloc = t >> 4;  // batch within block

    const int   hrel = C3_HREL[j];
    const float bj   = bias[j];

    // Filter -> registers (same address across the lanes sharing j -> L1).
    const float* __restrict__ wp = w + C3_WIDX[j] * 25;
    float wr[25];
#pragma unroll
    for (int i = 0; i < 25; ++i) wr[i] = wp[i];

    __syncthreads();

    const float* __restrict__ xp = &sx[bloc * XPITCH + hrel * 196];

    // 5-row x 14-col register sliding window over all 10 output rows.
    float xw[5][14];
#pragma unroll
    for (int r = 0; r < 4; ++r) {
        const float2* rp = (const float2*)(xp + r * 14);
#pragma unroll
        for (int i = 0; i < 7; ++i) {
            float2 v = rp[i];
            xw[r][2 * i]     = v.x;
            xw[r][2 * i + 1] = v.y;
        }
    }

    // Per-thread output plane: out[b][j][0..9][0..9], 100 floats contiguous,
    // float4-aligned (j*100 % 4 == 0).
    float* __restrict__ outp = out + ((size_t)blockIdx.x * NB + bloc) * 1600 + j * 100;
    float prev[10];

#pragma unroll
    for (int orow = 0; orow < 10; ++orow) {
        {
            const float2* rp = (const float2*)(xp + (orow + 4) * 14);
            float* d = xw[(orow + 4) % 5];
#pragma unroll
            for (int i = 0; i < 7; ++i) {
                float2 v = rp[i];
                d[2 * i]     = v.x;
                d[2 * i + 1] = v.y;
            }
        }

        float acc[10];
#pragma unroll
        for (int c = 0; c < 10; ++c) acc[c] = bj;

#pragma unroll
        for (int u = 0; u < 5; ++u) {
            const float* row = xw[(orow + u) % 5];
#pragma unroll
            for (int v = 0; v < 5; ++v) {
                const float wv = wr[u * 5 + v];
#pragma unroll
                for (int c = 0; c < 10; ++c)
                    acc[c] = fmaf(wv, row[c + v], acc[c]);
            }
        }

        if (orow & 1) {
            // Store the buffered row pair: 20 floats = 5 aligned float4
            // ((orow-1)*10 % 4 == 0 for odd orow).
            float4* __restrict__ dst = (float4*)(outp + (orow - 1) * 10);
            dst[0] = make_float4(prev[0], prev[1], prev[2], prev[3]);
            dst[1] = make_float4(prev[4], prev[5], prev[6], prev[7]);
            dst[2] = make_float4(prev[8], prev[9], acc[0], acc[1]);
            dst[3] = make_float4(acc[2],  acc[3],  acc[4],  acc[5]);
            dst[4] = make_float4(acc[6],  acc[7],  acc[8],  acc[9]);
        } else {
#pragma unroll
            for (int c = 0; c < 10; ++c) prev[c] = acc[c];
        }
    }
}

extern "C" void kernel_launch(void* const* d_in, const int* in_sizes, int n_in,
                              void* d_out, int out_size, void* d_ws, size_t ws_size,
                              hipStream_t stream) {
    const float* x    = (const float*)d_in[0];
    const float* w    = (const float*)d_in[1];
    const float* bias = (const float*)d_in[2];
    float* out        = (float*)d_out;

    const int B = in_sizes[0] / (6 * 14 * 14); // 65536
    const int nblocks = B / NB;                // 8192

    hipLaunchKernelGGL(c3_kernel, dim3(nblocks), dim3(THREADS), 0, stream,
                       x, w, bias, out);
}